// Round 1
// baseline (475.028 us; speedup 1.0000x reference)
//
#include <hip/hip_runtime.h>
#include <math.h>

#define HW 16384
#define B_ 8
#define C_ 256
#define S_ 64
#define K_ 8

__device__ __forceinline__ float sigmoidf_(float z) { return 1.f / (1.f + __expf(-z)); }

// ---------------- K0: kconst[k] = sum_c anchor^2 * inv2 ----------------
__global__ void k0_kconst(const float* __restrict__ anchor, const float* __restrict__ sigma_p,
                          float* __restrict__ kconst) {
    int k = threadIdx.x;
    if (k < K_) {
        float s = 0.f;
        for (int c = 0; c < C_; ++c) {
            float sg = sigmoidf_(sigma_p[k * C_ + c]);
            float a = anchor[k * C_ + c];
            s += a * a / (sg * sg);
        }
        kconst[k] = s;
    }
}

// ---------------- K1: fused x_proj + d2/softmax(soft) + cm ----------------
__global__ __launch_bounds__(512, 2) void k1_main(
    const float* __restrict__ x, const float* __restrict__ contour,
    const float* __restrict__ wproj, const float* __restrict__ bproj,
    const float* __restrict__ anchor, const float* __restrict__ sigma_p,
    const float* __restrict__ kconst,
    float* __restrict__ cm, float* __restrict__ xp, float* __restrict__ soft) {
    __shared__ float wl[S_ * C_];      // 64 KB
    __shared__ float ivl[K_ * C_];     // 8 KB
    __shared__ float aivl[K_ * C_];    // 8 KB
    __shared__ float bl[S_];
    __shared__ float kcl[K_];
    const int tid = threadIdx.x;
    const int b = blockIdx.y;
    const int n = blockIdx.x * 512 + tid;

    for (int i = tid; i < S_ * C_; i += 512) wl[i] = wproj[i];
    for (int i = tid; i < K_ * C_; i += 512) {
        float sg = sigmoidf_(sigma_p[i]);
        float iv = 1.f / (sg * sg);
        ivl[i] = iv;
        aivl[i] = anchor[i] * iv;
    }
    if (tid < S_) bl[tid] = bproj[tid];
    if (tid < K_) kcl[tid] = kconst[tid];
    __syncthreads();

    float acc[S_];
    float q1[K_], q2[K_];
#pragma unroll
    for (int s = 0; s < S_; ++s) acc[s] = 0.f;
#pragma unroll
    for (int k = 0; k < K_; ++k) { q1[k] = 0.f; q2[k] = 0.f; }

    const float* xb = x + (size_t)b * C_ * HW + n;
    float xv0 = xb[0], xv1 = xb[HW], xv2 = xb[2 * HW], xv3 = xb[3 * HW];
    for (int c = 0; c < C_; c += 4) {
        int cn = (c + 4 < C_) ? (c + 4) : 0;  // prefetch (wraps harmlessly on last iter)
        const float* p = xb + (size_t)cn * HW;
        float nx0 = p[0], nx1 = p[HW], nx2 = p[2 * HW], nx3 = p[3 * HW];
#pragma unroll
        for (int s = 0; s < S_; ++s) {
            const float4 w = *(const float4*)&wl[s * C_ + c];
            acc[s] = fmaf(w.x, xv0, fmaf(w.y, xv1, fmaf(w.z, xv2, fmaf(w.w, xv3, acc[s]))));
        }
        float x20 = xv0 * xv0, x21 = xv1 * xv1, x22 = xv2 * xv2, x23 = xv3 * xv3;
#pragma unroll
        for (int k = 0; k < K_; ++k) {
            const float4 a = *(const float4*)&aivl[k * C_ + c];
            q1[k] = fmaf(a.x, xv0, fmaf(a.y, xv1, fmaf(a.z, xv2, fmaf(a.w, xv3, q1[k]))));
            const float4 v = *(const float4*)&ivl[k * C_ + c];
            q2[k] = fmaf(v.x, x20, fmaf(v.y, x21, fmaf(v.z, x22, fmaf(v.w, x23, q2[k]))));
        }
        xv0 = nx0; xv1 = nx1; xv2 = nx2; xv3 = nx3;
    }

    // write x_proj (with bias)
    float* xpn = xp + (size_t)b * S_ * HW + n;
#pragma unroll
    for (int s = 0; s < S_; ++s) xpn[(size_t)s * HW] = acc[s] + bl[s];

    // soft = softmax_k(-0.5 * d2)
    float lg[K_], mx = -1e30f;
#pragma unroll
    for (int k = 0; k < K_; ++k) {
        lg[k] = -0.5f * (q2[k] - 2.f * q1[k] + kcl[k]);
        mx = fmaxf(mx, lg[k]);
    }
    float sm = 0.f;
#pragma unroll
    for (int k = 0; k < K_; ++k) { float e = __expf(lg[k] - mx); lg[k] = e; sm += e; }
    float inv = 1.f / sm;
    float* sp = soft + (size_t)b * K_ * HW + n;
#pragma unroll
    for (int k = 0; k < K_; ++k) sp[(size_t)k * HW] = lg[k] * inv;

    // cm = softmax(contour, ch)[1] = sigmoid(c1 - c0)
    float c0 = contour[(size_t)b * 2 * HW + n];
    float c1 = contour[(size_t)b * 2 * HW + HW + n];
    cm[(size_t)b * HW + n] = sigmoidf_(c1 - c0);
}

// ---------------- K2: adaptive-pool cropped bins -> x_anchor (B,64,64) ----------------
__global__ void k2_anchor(const float* __restrict__ xp, const float* __restrict__ cm,
                          float* __restrict__ xa) {
    __shared__ float col[128];
    const int i = blockIdx.x;   // h-bin index (crop): actual bin = i+1
    const int s = blockIdx.y;
    const int b = blockIdx.z;
    const int w = threadIdx.x;  // 0..127
    const int h0 = ((i + 1) * 128) / 10;
    const int h1 = ((i + 2) * 128 + 9) / 10;
    const float* xps = xp + ((size_t)b * S_ + s) * HW;
    const float* cmb = cm + (size_t)b * HW;
    float v = 0.f;
    for (int h = h0; h < h1; ++h) v += xps[h * 128 + w] * cmb[h * 128 + w];
    col[w] = v;
    __syncthreads();
    if (w < 8) {
        const int j = w;
        const int w0 = ((j + 1) * 128) / 10;
        const int w1 = ((j + 2) * 128 + 9) / 10;
        float sum = 0.f;
        for (int t = w0; t < w1; ++t) sum += col[t];
        xa[((size_t)b * S_ + s) * 64 + i * 8 + j] = sum / (float)((h1 - h0) * (w1 - w0));
    }
}

// ---------------- K3: proj = softmax_m( x_anchor^T(s,m) . x_proj(s,n) ), in place ----------------
__global__ __launch_bounds__(256) void k3_proj(const float* __restrict__ xa, float* __restrict__ xp) {
    __shared__ float xal[64 * 64];
    const int b = blockIdx.y, tid = threadIdx.x;
    const int n = blockIdx.x * 256 + tid;
    for (int i = tid; i < 4096; i += 256) xal[i] = xa[(size_t)b * 4096 + i];
    __syncthreads();
    float p[64];
#pragma unroll
    for (int m = 0; m < 64; ++m) p[m] = 0.f;
    float* xpb = xp + (size_t)b * S_ * HW + n;
    float xv = xpb[0];
    for (int s = 0; s < 64; ++s) {
        float xnext = (s < 63) ? xpb[(size_t)(s + 1) * HW] : 0.f;
#pragma unroll
        for (int m = 0; m < 64; m += 4) {
            const float4 a = *(const float4*)&xal[s * 64 + m];
            p[m] = fmaf(a.x, xv, p[m]);
            p[m + 1] = fmaf(a.y, xv, p[m + 1]);
            p[m + 2] = fmaf(a.z, xv, p[m + 2]);
            p[m + 3] = fmaf(a.w, xv, p[m + 3]);
        }
        xv = xnext;
    }
    float mx = -1e30f;
#pragma unroll
    for (int m = 0; m < 64; ++m) mx = fmaxf(mx, p[m]);
    float sm = 0.f;
#pragma unroll
    for (int m = 0; m < 64; ++m) { float e = __expf(p[m] - mx); p[m] = e; sm += e; }
    float inv = 1.f / sm;
#pragma unroll
    for (int m = 0; m < 64; ++m) xpb[(size_t)m * HW] = p[m] * inv;
}

// ---------------- K5: wsum[b,k,c] = sum_n soft[b,k,n] * x[b,c,n] ----------------
__global__ __launch_bounds__(256) void k5_wsum(const float* __restrict__ x,
                                               const float* __restrict__ soft,
                                               float* __restrict__ wsum) {
    const int b = blockIdx.y;
    const int c0 = blockIdx.x * 4;
    const int tid = threadIdx.x;
    float a[32];
#pragma unroll
    for (int i = 0; i < 32; ++i) a[i] = 0.f;
    const float* sb = soft + (size_t)b * K_ * HW;
    const float* xb = x + ((size_t)b * C_ + c0) * HW;
    for (int n = tid; n < HW; n += 256) {
        float sv[8];
#pragma unroll
        for (int k = 0; k < 8; ++k) sv[k] = sb[(size_t)k * HW + n];
#pragma unroll
        for (int ci = 0; ci < 4; ++ci) {
            float xv = xb[(size_t)ci * HW + n];
#pragma unroll
            for (int k = 0; k < 8; ++k) a[ci * 8 + k] = fmaf(sv[k], xv, a[ci * 8 + k]);
        }
    }
    __shared__ float red[128];
    const int lane = tid & 63, wid = tid >> 6;
#pragma unroll
    for (int o = 0; o < 32; ++o) {
        float v = a[o];
#pragma unroll
        for (int m = 32; m; m >>= 1) v += __shfl_xor(v, m, 64);
        if (lane == 0) red[wid * 32 + o] = v;
    }
    __syncthreads();
    if (tid < 32) {
        float r = red[tid] + red[32 + tid] + red[64 + tid] + red[96 + tid];
        int ci = tid >> 3, k = tid & 7;
        wsum[((size_t)b * K_ + k) * C_ + c0 + ci] = r;
    }
}

// ---------------- K6: ssum, nodes, normalize, 3x GCN, relu -> g ----------------
__device__ __forceinline__ float blockSum256(float v, volatile float* sc) {
#pragma unroll
    for (int m = 32; m; m >>= 1) v += __shfl_xor(v, m, 64);
    const int wid = threadIdx.x >> 6, lane = threadIdx.x & 63;
    __syncthreads();
    if (lane == 0) sc[wid] = v;
    __syncthreads();
    return sc[0] + sc[1] + sc[2] + sc[3];
}

__global__ __launch_bounds__(256) void k6_gcn(const float* __restrict__ soft,
                                              const float* __restrict__ wsum,
                                              const float* __restrict__ anchor,
                                              const float* __restrict__ sigma_p,
                                              const float* __restrict__ w1,
                                              const float* __restrict__ w2,
                                              const float* __restrict__ w3,
                                              float* __restrict__ gout) {
    const int b = blockIdx.x;
    const int tid = threadIdx.x;
    __shared__ float g_lds[2048];       // g[c][k] at [c*8+k]  (== flat[k*256+c] view)
    __shared__ float A[64];
    __shared__ float wchunk[64 * 256];  // 64 KB
    __shared__ float sc[4];

    // ssum
    float ssk[8];
#pragma unroll
    for (int k = 0; k < 8; ++k) {
        float v = 0.f;
        const float* sp = soft + ((size_t)b * K_ + k) * HW;
        for (int n = tid; n < HW; n += 256) v += sp[n];
        ssk[k] = blockSum256(v, sc);
    }

    // nodes (thread = channel c)
    const int c = tid;
    float node[8];
#pragma unroll
    for (int k = 0; k < 8; ++k) {
        float sg = sigmoidf_(sigma_p[k * C_ + c]);
        float w = wsum[((size_t)b * K_ + k) * C_ + c];
        node[k] = (w - anchor[k * C_ + c] * ssk[k]) / sg / (ssk[k] + 1e-9f);
    }
#pragma unroll
    for (int k = 0; k < 8; ++k) {
        float rn = blockSum256(node[k] * node[k], sc);
        node[k] /= fmaxf(sqrtf(rn), 1e-12f);
    }
    float fs = 0.f;
#pragma unroll
    for (int k = 0; k < 8; ++k) fs += node[k] * node[k];
    float fn = blockSum256(fs, sc);
    float finv = 1.f / fmaxf(sqrtf(fn), 1e-12f);
#pragma unroll
    for (int k = 0; k < 8; ++k) g_lds[k * C_ + c] = node[k] * finv;  // flat layout
    __syncthreads();

    const float* Ws[3] = {w1, w2, w3};
    for (int L = 0; L < 3; ++L) {
        // A[p][q] = sum_i g[i][p] g[i][q]
        if (tid < 64) {
            int p = tid >> 3, q = tid & 7;
            float s = 0.f;
            for (int i = 0; i < 256; ++i) s += g_lds[i * 8 + p] * g_lds[i * 8 + q];
            A[tid] = s;
        }
        __syncthreads();
        if (tid < 8) {  // row softmax
            float mx = -1e30f;
            for (int j = 0; j < 8; ++j) mx = fmaxf(mx, A[tid * 8 + j]);
            float sm = 0.f;
            for (int j = 0; j < 8; ++j) { float e = __expf(A[tid * 8 + j] - mx); A[tid * 8 + j] = e; sm += e; }
            float iv = 1.f / sm;
            for (int j = 0; j < 8; ++j) A[tid * 8 + j] *= iv;
        }
        __syncthreads();
        // support[j][d=tid] = sum_c g[c][j] * W[c][d]
        float sup[8];
#pragma unroll
        for (int j = 0; j < 8; ++j) sup[j] = 0.f;
        const float* W = Ws[L];
        for (int ch = 0; ch < 4; ++ch) {
            const float4* src = (const float4*)(W + (size_t)ch * 64 * 256);
            float4* dst = (float4*)wchunk;
            for (int i = tid; i < 64 * 256 / 4; i += 256) dst[i] = src[i];
            __syncthreads();
            for (int cc = 0; cc < 64; ++cc) {
                int cg = ch * 64 + cc;
                float wv = wchunk[cc * 256 + tid];
#pragma unroll
                for (int j = 0; j < 8; ++j) sup[j] = fmaf(g_lds[cg * 8 + j], wv, sup[j]);
            }
            __syncthreads();
        }
        // g_new[d][k] = sum_j adj[k][j] * support[j][d]
        float gn[8];
#pragma unroll
        for (int k = 0; k < 8; ++k) {
            float s = 0.f;
#pragma unroll
            for (int j = 0; j < 8; ++j) s += A[k * 8 + j] * sup[j];
            gn[k] = s;
        }
        __syncthreads();
#pragma unroll
        for (int k = 0; k < 8; ++k) g_lds[tid * 8 + k] = gn[k];
        __syncthreads();
    }
#pragma unroll
    for (int k = 0; k < 8; ++k)
        gout[(size_t)b * 2048 + tid * 8 + k] = fmaxf(g_lds[tid * 8 + k], 0.f);
}

extern "C" void kernel_launch(void* const* d_in, const int* in_sizes, int n_in,
                              void* d_out, int out_size, void* d_ws, size_t ws_size,
                              hipStream_t stream) {
    const float* x = (const float*)d_in[0];
    const float* contour = (const float*)d_in[1];
    // d_in[2]/d_in[3] (conv_state_*) are unused by the reference
    const float* wproj = (const float*)d_in[4];
    const float* bproj = (const float*)d_in[5];
    const float* anchor = (const float*)d_in[6];
    const float* sigma_p = (const float*)d_in[7];
    const float* w1 = (const float*)d_in[8];
    const float* w2 = (const float*)d_in[9];
    const float* w3 = (const float*)d_in[10];

    float* out = (float*)d_out;
    float* g_out = out;                        // (B,256,8)
    float* xp = out + 16384;                   // proj region (B,64,HW): x_proj, then proj in-place
    float* soft = out + 16384 + 8388608;       // (B,8,HW)

    float* ws = (float*)d_ws;
    float* cm = ws;                 // B*HW
    float* xa = ws + 131072;        // B*64*64
    float* wsum = ws + 163840;      // B*8*256
    float* kconst = ws + 180224;    // 8

    k0_kconst<<<1, 64, 0, stream>>>(anchor, sigma_p, kconst);
    k1_main<<<dim3(32, B_), 512, 0, stream>>>(x, contour, wproj, bproj, anchor, sigma_p,
                                              kconst, cm, xp, soft);
    k2_anchor<<<dim3(8, 64, B_), 128, 0, stream>>>(xp, cm, xa);
    k3_proj<<<dim3(64, B_), 256, 0, stream>>>(xa, xp);
    k5_wsum<<<dim3(64, B_), 256, 0, stream>>>(x, soft, wsum);
    k6_gcn<<<B_, 256, 0, stream>>>(soft, wsum, anchor, sigma_p, w1, w2, w3, g_out);
}

// Round 2
// 326.999 us; speedup vs baseline: 1.4527x; 1.4527x over previous
//
#include <hip/hip_runtime.h>
#include <math.h>

#define HW 16384
#define B_ 8
#define C_ 256
#define S_ 64
#define K_ 8

__device__ __forceinline__ float sigmoidf_(float z) { return 1.f / (1.f + __expf(-z)); }

// ---------------- K0: kconst[k] = sum_c anchor^2 * inv2 ----------------
__global__ void k0_kconst(const float* __restrict__ anchor, const float* __restrict__ sigma_p,
                          float* __restrict__ kconst) {
    int k = threadIdx.x;
    if (k < K_) {
        float s = 0.f;
        for (int c = 0; c < C_; ++c) {
            float sg = sigmoidf_(sigma_p[k * C_ + c]);
            float a = anchor[k * C_ + c];
            s += a * a / (sg * sg);
        }
        kconst[k] = s;
    }
}

// ---------------- K1: fused x_proj + d2/softmax(soft) + cm ----------------
__global__ __launch_bounds__(512, 2) void k1_main(
    const float* __restrict__ x, const float* __restrict__ contour,
    const float* __restrict__ wproj, const float* __restrict__ bproj,
    const float* __restrict__ anchor, const float* __restrict__ sigma_p,
    const float* __restrict__ kconst,
    float* __restrict__ cm, float* __restrict__ xp, float* __restrict__ soft) {
    __shared__ float wl[S_ * C_];      // 64 KB
    __shared__ float ivl[K_ * C_];     // 8 KB
    __shared__ float aivl[K_ * C_];    // 8 KB
    __shared__ float bl[S_];
    __shared__ float kcl[K_];
    const int tid = threadIdx.x;
    const int b = blockIdx.y;
    const int n = blockIdx.x * 512 + tid;

    for (int i = tid; i < S_ * C_; i += 512) wl[i] = wproj[i];
    for (int i = tid; i < K_ * C_; i += 512) {
        float sg = sigmoidf_(sigma_p[i]);
        float iv = 1.f / (sg * sg);
        ivl[i] = iv;
        aivl[i] = anchor[i] * iv;
    }
    if (tid < S_) bl[tid] = bproj[tid];
    if (tid < K_) kcl[tid] = kconst[tid];
    __syncthreads();

    float acc[S_];
    float q1[K_], q2[K_];
#pragma unroll
    for (int s = 0; s < S_; ++s) acc[s] = 0.f;
#pragma unroll
    for (int k = 0; k < K_; ++k) { q1[k] = 0.f; q2[k] = 0.f; }

    const float* xb = x + (size_t)b * C_ * HW + n;
    float xv0 = xb[0], xv1 = xb[HW], xv2 = xb[2 * HW], xv3 = xb[3 * HW];
    for (int c = 0; c < C_; c += 4) {
        int cn = (c + 4 < C_) ? (c + 4) : 0;  // prefetch (wraps harmlessly on last iter)
        const float* p = xb + (size_t)cn * HW;
        float nx0 = p[0], nx1 = p[HW], nx2 = p[2 * HW], nx3 = p[3 * HW];
#pragma unroll
        for (int s = 0; s < S_; ++s) {
            const float4 w = *(const float4*)&wl[s * C_ + c];
            acc[s] = fmaf(w.x, xv0, fmaf(w.y, xv1, fmaf(w.z, xv2, fmaf(w.w, xv3, acc[s]))));
        }
        float x20 = xv0 * xv0, x21 = xv1 * xv1, x22 = xv2 * xv2, x23 = xv3 * xv3;
#pragma unroll
        for (int k = 0; k < K_; ++k) {
            const float4 a = *(const float4*)&aivl[k * C_ + c];
            q1[k] = fmaf(a.x, xv0, fmaf(a.y, xv1, fmaf(a.z, xv2, fmaf(a.w, xv3, q1[k]))));
            const float4 v = *(const float4*)&ivl[k * C_ + c];
            q2[k] = fmaf(v.x, x20, fmaf(v.y, x21, fmaf(v.z, x22, fmaf(v.w, x23, q2[k]))));
        }
        xv0 = nx0; xv1 = nx1; xv2 = nx2; xv3 = nx3;
    }

    // write x_proj (with bias)
    float* xpn = xp + (size_t)b * S_ * HW + n;
#pragma unroll
    for (int s = 0; s < S_; ++s) xpn[(size_t)s * HW] = acc[s] + bl[s];

    // soft = softmax_k(-0.5 * d2)
    float lg[K_], mx = -1e30f;
#pragma unroll
    for (int k = 0; k < K_; ++k) {
        lg[k] = -0.5f * (q2[k] - 2.f * q1[k] + kcl[k]);
        mx = fmaxf(mx, lg[k]);
    }
    float sm = 0.f;
#pragma unroll
    for (int k = 0; k < K_; ++k) { float e = __expf(lg[k] - mx); lg[k] = e; sm += e; }
    float inv = 1.f / sm;
    float* sp = soft + (size_t)b * K_ * HW + n;
#pragma unroll
    for (int k = 0; k < K_; ++k) sp[(size_t)k * HW] = lg[k] * inv;

    // cm = softmax(contour, ch)[1] = sigmoid(c1 - c0)
    float c0 = contour[(size_t)b * 2 * HW + n];
    float c1 = contour[(size_t)b * 2 * HW + HW + n];
    cm[(size_t)b * HW + n] = sigmoidf_(c1 - c0);
}

// ---------------- K2: adaptive-pool cropped bins -> x_anchor (B,64,64) ----------------
__global__ void k2_anchor(const float* __restrict__ xp, const float* __restrict__ cm,
                          float* __restrict__ xa) {
    __shared__ float col[128];
    const int i = blockIdx.x;   // h-bin index (crop): actual bin = i+1
    const int s = blockIdx.y;
    const int b = blockIdx.z;
    const int w = threadIdx.x;  // 0..127
    const int h0 = ((i + 1) * 128) / 10;
    const int h1 = ((i + 2) * 128 + 9) / 10;
    const float* xps = xp + ((size_t)b * S_ + s) * HW;
    const float* cmb = cm + (size_t)b * HW;
    float v = 0.f;
    for (int h = h0; h < h1; ++h) v += xps[h * 128 + w] * cmb[h * 128 + w];
    col[w] = v;
    __syncthreads();
    if (w < 8) {
        const int j = w;
        const int w0 = ((j + 1) * 128) / 10;
        const int w1 = ((j + 2) * 128 + 9) / 10;
        float sum = 0.f;
        for (int t = w0; t < w1; ++t) sum += col[t];
        xa[((size_t)b * S_ + s) * 64 + i * 8 + j] = sum / (float)((h1 - h0) * (w1 - w0));
    }
}

// ---------------- K3: proj = softmax_m( x_anchor^T(s,m) . x_proj(s,n) ), in place ----------------
__global__ __launch_bounds__(256) void k3_proj(const float* __restrict__ xa, float* __restrict__ xp) {
    __shared__ float xal[64 * 64];
    const int b = blockIdx.y, tid = threadIdx.x;
    const int n = blockIdx.x * 256 + tid;
    for (int i = tid; i < 4096; i += 256) xal[i] = xa[(size_t)b * 4096 + i];
    __syncthreads();
    float p[64];
#pragma unroll
    for (int m = 0; m < 64; ++m) p[m] = 0.f;
    float* xpb = xp + (size_t)b * S_ * HW + n;
    float xv = xpb[0];
    for (int s = 0; s < 64; ++s) {
        float xnext = (s < 63) ? xpb[(size_t)(s + 1) * HW] : 0.f;
#pragma unroll
        for (int m = 0; m < 64; m += 4) {
            const float4 a = *(const float4*)&xal[s * 64 + m];
            p[m] = fmaf(a.x, xv, p[m]);
            p[m + 1] = fmaf(a.y, xv, p[m + 1]);
            p[m + 2] = fmaf(a.z, xv, p[m + 2]);
            p[m + 3] = fmaf(a.w, xv, p[m + 3]);
        }
        xv = xnext;
    }
    float mx = -1e30f;
#pragma unroll
    for (int m = 0; m < 64; ++m) mx = fmaxf(mx, p[m]);
    float sm = 0.f;
#pragma unroll
    for (int m = 0; m < 64; ++m) { float e = __expf(p[m] - mx); p[m] = e; sm += e; }
    float inv = 1.f / sm;
#pragma unroll
    for (int m = 0; m < 64; ++m) xpb[(size_t)m * HW] = p[m] * inv;
}

// ---------------- K4: ssum[b,k] = sum_n soft[b,k,n] ----------------
__global__ __launch_bounds__(256) void k4_ssum(const float* __restrict__ soft,
                                               float* __restrict__ ssumg) {
    const int bk = blockIdx.x;  // 0..63
    const int tid = threadIdx.x;
    const float4* sp = (const float4*)(soft + (size_t)bk * HW);
    float v = 0.f;
    for (int i = tid; i < HW / 4; i += 256) {
        float4 t = sp[i];
        v += (t.x + t.y) + (t.z + t.w);
    }
#pragma unroll
    for (int m = 32; m; m >>= 1) v += __shfl_xor(v, m, 64);
    __shared__ float red[4];
    const int wid = tid >> 6, lane = tid & 63;
    if (lane == 0) red[wid] = v;
    __syncthreads();
    if (tid == 0) ssumg[bk] = red[0] + red[1] + red[2] + red[3];
}

// ---------------- K5: wsum[b,k,c] = sum_n soft[b,k,n] * x[b,c,n] ----------------
__global__ __launch_bounds__(256) void k5_wsum(const float* __restrict__ x,
                                               const float* __restrict__ soft,
                                               float* __restrict__ wsum) {
    const int b = blockIdx.y;
    const int c0 = blockIdx.x * 4;
    const int tid = threadIdx.x;
    float a[32];
#pragma unroll
    for (int i = 0; i < 32; ++i) a[i] = 0.f;
    const float* sb = soft + (size_t)b * K_ * HW;
    const float* xb = x + ((size_t)b * C_ + c0) * HW;
    for (int n = tid; n < HW; n += 256) {
        float sv[8];
#pragma unroll
        for (int k = 0; k < 8; ++k) sv[k] = sb[(size_t)k * HW + n];
#pragma unroll
        for (int ci = 0; ci < 4; ++ci) {
            float xv = xb[(size_t)ci * HW + n];
#pragma unroll
            for (int k = 0; k < 8; ++k) a[ci * 8 + k] = fmaf(sv[k], xv, a[ci * 8 + k]);
        }
    }
    __shared__ float red[128];
    const int lane = tid & 63, wid = tid >> 6;
#pragma unroll
    for (int o = 0; o < 32; ++o) {
        float v = a[o];
#pragma unroll
        for (int m = 32; m; m >>= 1) v += __shfl_xor(v, m, 64);
        if (lane == 0) red[wid * 32 + o] = v;
    }
    __syncthreads();
    if (tid < 32) {
        float r = red[tid] + red[32 + tid] + red[64 + tid] + red[96 + tid];
        int ci = tid >> 3, k = tid & 7;
        wsum[((size_t)b * K_ + k) * C_ + c0 + ci] = r;
    }
}

// ---------------- K6: nodes, normalize, 3x GCN, relu -> g ----------------
__device__ __forceinline__ float blockSum256(float v, volatile float* sc) {
#pragma unroll
    for (int m = 32; m; m >>= 1) v += __shfl_xor(v, m, 64);
    const int wid = threadIdx.x >> 6, lane = threadIdx.x & 63;
    __syncthreads();
    if (lane == 0) sc[wid] = v;
    __syncthreads();
    return sc[0] + sc[1] + sc[2] + sc[3];
}

__global__ __launch_bounds__(256) void k6_gcn(const float* __restrict__ ssumg,
                                              const float* __restrict__ wsum,
                                              const float* __restrict__ anchor,
                                              const float* __restrict__ sigma_p,
                                              const float* __restrict__ w1,
                                              const float* __restrict__ w2,
                                              const float* __restrict__ w3,
                                              float* __restrict__ gout) {
    const int b = blockIdx.x;
    const int tid = threadIdx.x;
    const int lane = tid & 63, wid = tid >> 6;
    __shared__ float g_lds[2048];  // g[c][k] at [c*8+k]  (== flat[k*256+c] view)
    __shared__ float A[64];
    __shared__ float sc[4];
    __shared__ float red8[4][8];
    __shared__ float ssk_s[8];

    if (tid < 8) ssk_s[tid] = ssumg[b * 8 + tid];
    __syncthreads();
    float ssk[8];
#pragma unroll
    for (int k = 0; k < 8; ++k) ssk[k] = ssk_s[k];

    // nodes (thread = channel c)
    const int c = tid;
    float node[8];
#pragma unroll
    for (int k = 0; k < 8; ++k) {
        float sg = sigmoidf_(sigma_p[k * C_ + c]);
        float w = wsum[((size_t)b * K_ + k) * C_ + c];
        node[k] = (w - anchor[k * C_ + c] * ssk[k]) / sg / (ssk[k] + 1e-9f);
    }
    // batched row-norm reduction: rn[k] = sum_c node[k]^2
    float rn[8];
#pragma unroll
    for (int k = 0; k < 8; ++k) rn[k] = node[k] * node[k];
#pragma unroll
    for (int m = 32; m; m >>= 1) {
#pragma unroll
        for (int k = 0; k < 8; ++k) rn[k] += __shfl_xor(rn[k], m, 64);
    }
    if (lane == 0) {
#pragma unroll
        for (int k = 0; k < 8; ++k) red8[wid][k] = rn[k];
    }
    __syncthreads();
#pragma unroll
    for (int k = 0; k < 8; ++k) {
        float t = red8[0][k] + red8[1][k] + red8[2][k] + red8[3][k];
        node[k] /= fmaxf(sqrtf(t), 1e-12f);
    }
    float fs = 0.f;
#pragma unroll
    for (int k = 0; k < 8; ++k) fs += node[k] * node[k];
    float fn = blockSum256(fs, sc);
    float finv = 1.f / fmaxf(sqrtf(fn), 1e-12f);
#pragma unroll
    for (int k = 0; k < 8; ++k) g_lds[tid * 8 + k] = node[k] * finv;  // g[c][k], c=tid
    __syncthreads();

    const float* Ws[3] = {w1, w2, w3};
    for (int L = 0; L < 3; ++L) {
        // A[p][q] = sum_i g[i][p] g[i][q], 4 threads per (p,q) pair
        {
            const int pair = tid >> 2, part = tid & 3;  // pair 0..63
            const int p = pair >> 3, q = pair & 7;
            float s = 0.f;
            for (int i = part * 64; i < part * 64 + 64; ++i)
                s += g_lds[i * 8 + p] * g_lds[i * 8 + q];
            s += __shfl_xor(s, 1, 64);
            s += __shfl_xor(s, 2, 64);
            if (part == 0) A[pair] = s;
        }
        __syncthreads();
        if (tid < 8) {  // row softmax
            float mx = -1e30f;
            for (int j = 0; j < 8; ++j) mx = fmaxf(mx, A[tid * 8 + j]);
            float sm = 0.f;
            for (int j = 0; j < 8; ++j) { float e = __expf(A[tid * 8 + j] - mx); A[tid * 8 + j] = e; sm += e; }
            float iv = 1.f / sm;
            for (int j = 0; j < 8; ++j) A[tid * 8 + j] *= iv;
        }
        __syncthreads();
        // support[j][d=tid] = sum_c g[c][j] * W[c][d] — W direct global->reg, double-buffered
        float sup[8];
#pragma unroll
        for (int j = 0; j < 8; ++j) sup[j] = 0.f;
        const float* W = Ws[L];
        float wv[8], wn[8];
#pragma unroll
        for (int i = 0; i < 8; ++i) wv[i] = W[(size_t)i * 256 + tid];
        for (int c0 = 0; c0 < 256; c0 += 8) {
            if (c0 + 8 < 256) {
#pragma unroll
                for (int i = 0; i < 8; ++i) wn[i] = W[(size_t)(c0 + 8 + i) * 256 + tid];
            }
#pragma unroll
            for (int i = 0; i < 8; ++i) {
#pragma unroll
                for (int j = 0; j < 8; ++j)
                    sup[j] = fmaf(g_lds[(c0 + i) * 8 + j], wv[i], sup[j]);
            }
#pragma unroll
            for (int i = 0; i < 8; ++i) wv[i] = wn[i];
        }
        // g_new[d][k] = sum_j adj[k][j] * support[j][d]
        float gn[8];
#pragma unroll
        for (int k = 0; k < 8; ++k) {
            float s = 0.f;
#pragma unroll
            for (int j = 0; j < 8; ++j) s += A[k * 8 + j] * sup[j];
            gn[k] = s;
        }
        __syncthreads();
#pragma unroll
        for (int k = 0; k < 8; ++k) g_lds[tid * 8 + k] = gn[k];
        __syncthreads();
    }
#pragma unroll
    for (int k = 0; k < 8; ++k)
        gout[(size_t)b * 2048 + tid * 8 + k] = fmaxf(g_lds[tid * 8 + k], 0.f);
}

extern "C" void kernel_launch(void* const* d_in, const int* in_sizes, int n_in,
                              void* d_out, int out_size, void* d_ws, size_t ws_size,
                              hipStream_t stream) {
    const float* x = (const float*)d_in[0];
    const float* contour = (const float*)d_in[1];
    const float* wproj = (const float*)d_in[4];
    const float* bproj = (const float*)d_in[5];
    const float* anchor = (const float*)d_in[6];
    const float* sigma_p = (const float*)d_in[7];
    const float* w1 = (const float*)d_in[8];
    const float* w2 = (const float*)d_in[9];
    const float* w3 = (const float*)d_in[10];

    float* out = (float*)d_out;
    float* g_out = out;                        // (B,256,8)
    float* xp = out + 16384;                   // proj region (B,64,HW): x_proj, then proj in-place
    float* soft = out + 16384 + 8388608;       // (B,8,HW)

    float* ws = (float*)d_ws;
    float* cm = ws;                 // B*HW
    float* xa = ws + 131072;        // B*64*64
    float* wsum = ws + 163840;      // B*8*256
    float* kconst = ws + 180224;    // 8
    float* ssumg = ws + 180232;     // B*8

    k0_kconst<<<1, 64, 0, stream>>>(anchor, sigma_p, kconst);
    k1_main<<<dim3(32, B_), 512, 0, stream>>>(x, contour, wproj, bproj, anchor, sigma_p,
                                              kconst, cm, xp, soft);
    k4_ssum<<<B_ * K_, 256, 0, stream>>>(soft, ssumg);
    k2_anchor<<<dim3(8, 64, B_), 128, 0, stream>>>(xp, cm, xa);
    k3_proj<<<dim3(64, B_), 256, 0, stream>>>(xa, xp);
    k5_wsum<<<dim3(64, B_), 256, 0, stream>>>(x, soft, wsum);
    k6_gcn<<<B_, 256, 0, stream>>>(ssumg, wsum, anchor, sigma_p, w1, w2, w3, g_out);
}